// Round 13
// baseline (2645.977 us; speedup 1.0000x reference)
//
#include <hip/hip_runtime.h>
#include <cstddef>

#define Bn 32
#define Sn 2048
#define Hn 256
#define Ln 2
#define CHUNK 32
#define NCHUNK (Sn / CHUNK)   // 64
#define PACE 2                // proj1 runs at most PACE+1 chunks ahead of rec1

#define PSTR 10
#define PBUF (Hn * PSTR)      // 2560 words per partial buffer

#define FPAD 32               // one flag per 128B line
#define NFL (3 * Bn)          // xp1, y1, xp2 per batch

typedef float f32x2 __attribute__((ext_vector_type(2)));
typedef float f32x4 __attribute__((ext_vector_type(4)));

// ---------------------------------------------------------------------------
// ZERO-FENCE pipeline (r10-12) with COALESCED sc1 traffic (new):
//  - producers make cross-block data L3-visible via agent-scope stores, now
//    16B global_store_dwordx4 ... sc1 (was per-scalar: 164M 4B transactions
//    at WRITE_SIZE=655MB -- suspected tax on rec's latency-critical loads)
//  - rec y-writes move OUT of the step loop into a per-chunk LDS buffer,
//    flushed as coalesced 16B stores at chunk end
//  - consumers read normal-cached except provable stale-L2 cases (rec2's xp
//    aliases co-XCD rec1's cached xp1; both recs' 2 boundary prefetch rows)
// Flag slots: (0,b) xp1 ready (proj1) | (1,b) y1 done (rec1, also paces
// proj1) | (2,b) xp2 ready (proj2).
// ---------------------------------------------------------------------------
__device__ unsigned g_flags[NFL * FPAD];

__global__ void zero_flags_k() {
  int i = threadIdx.x;
  if (i < NFL)
    __hip_atomic_store(&g_flags[i * FPAD], 0u, __ATOMIC_RELAXED,
                       __HIP_MEMORY_SCOPE_AGENT);
}

__device__ __forceinline__ float tanh_fast(float x) {
  // tanh(x) = 1 - 2/(exp(2x)+1); saturates correctly at +/-inf
  float e = __expf(2.0f * x);
  return 1.0f - 2.0f / (e + 1.0f);
}

// sc1 (agent-scope) relaxed scalar load: bypasses non-coherent L2.
__device__ __forceinline__ float ldg_dev(const float* p) {
  return __hip_atomic_load(p, __ATOMIC_RELAXED, __HIP_MEMORY_SCOPE_AGENT);
}
// coalesced 16B agent-scope store (write-through to the L3 coherence point)
__device__ __forceinline__ void stg_dev4(float* p, f32x4 v) {
  asm volatile("global_store_dwordx4 %0, %1, off sc1"
               :: "v"(p), "v"(v) : "memory");
}

// pure poll (no fence); s_sleep(32) ~1us granularity for true waiters
__device__ __forceinline__ void poll_ge(unsigned* f, unsigned tgt) {
  while (__hip_atomic_load(f, __ATOMIC_RELAXED, __HIP_MEMORY_SCOPE_AGENT) < tgt)
    __builtin_amdgcn_s_sleep(32);
}

// publisher: drain (sc1 write-through) stores, barrier, t0 stores flag.
__device__ __forceinline__ void publish(unsigned* f, unsigned val, int t) {
  asm volatile("s_waitcnt vmcnt(0)" ::: "memory");
  __syncthreads();
  if (t == 0)
    __hip_atomic_store(f, val, __ATOMIC_RELAXED, __HIP_MEMORY_SCOPE_AGENT);
}

// ---------------------------------------------------------------------------
// Recurrence body — r11 step arithmetic unchanged (pk_fma FMA, stride-10
// swizzled slot-major partials, no-shfl 8-slot reduce, hbuf h-exchange,
// single raw s_barrier/step, depth-2 xp prefetch). NEW: y accumulates in
// LDS ybuf (one conflict-free ds_write/step; no global store in the loop),
// flushed per chunk as 4x dwordx4 (sc1 for rec1, cached for rec2-final).
// Flush race-safety: rec2 overwrites y1[c] with y2[c] only after polling
// xp2[c], i.e. after proj2 finished reading y1[c] (same order as r10-12).
// ---------------------------------------------------------------------------
template <bool XP_SC1, bool Y_SC1>
__device__ void rec_body(const float* __restrict__ xp_b,
                         const float* __restrict__ Whh,
                         const float* __restrict__ bhh,
                         const float* __restrict__ h0_b,
                         float* __restrict__ y_b,
                         float* __restrict__ hfin_b,
                         unsigned* waitf, unsigned* pub,
                         float* part, float* hbuf, float* ybuf) {
  const int t = threadIdx.x;
  const int lane = t & 63;
  const int w = t >> 6;                   // 0..7
  const int ocol = 32 * w + (lane & 31);  // output this lane reduces

  // Wreg[r][c2] = (Whh[lane+64r][32w+2c2], Whh[lane+64r][32w+2c2+1])
  f32x2 Wreg[4][16];
#pragma unroll
  for (int r = 0; r < 4; ++r)
#pragma unroll
    for (int q = 0; q < 8; ++q) {
      float4 v = *(const float4*)&Whh[(size_t)(lane + 64 * r) * Hn + 32 * w + 4 * q];
      Wreg[r][2 * q + 0] = f32x2{v.x, v.y};
      Wreg[r][2 * q + 1] = f32x2{v.z, v.w};
    }
#pragma unroll
  for (int r = 0; r < 4; ++r)
#pragma unroll
    for (int c = 0; c < 16; ++c)
      asm("" : "+v"(Wreg[r][c]));

  // partial write base: row = lane(+64r), slot = w ^ ((lane>>3)&3)
  const int pw0 = PSTR * lane + (w ^ ((lane >> 3) & 3));
  const float bias = bhh[ocol];

  f32x2 hv[16];
#pragma unroll
  for (int j = 0; j < 8; ++j) {
    float4 v = *(const float4*)&h0_b[32 * w + 4 * j];
    hv[2 * j + 0] = f32x2{v.x, v.y};
    hv[2 * j + 1] = f32x2{v.z, v.w};
  }

  for (int c = 0; c < NCHUNK; ++c) {
    // acquire this chunk's xp: pure poll, no fence
    if (t == 0) poll_ge(waitf, c + 1);
    __syncthreads();

    const int s0 = c * CHUNK;
    // sc1 reload of the two rows our pre-flag cross-chunk prefetch touched
    float xp_cur = ldg_dev(&xp_b[(size_t)s0 * Hn + ocol]);
    float xp_n1  = ldg_dev(&xp_b[(size_t)(s0 + 1) * Hn + ocol]);

    for (int ss = 0; ss < CHUNK; ++ss) {
      const int s = s0 + ss;
      // depth-2 prefetch: consumed two steps later
      float xp_n2 = 0.0f;
      if (s + 2 < Sn)
        xp_n2 = XP_SC1 ? ldg_dev(&xp_b[(size_t)(s + 2) * Hn + ocol])
                       : xp_b[(size_t)(s + 2) * Hn + ocol];

      // ---- FMA phase: 64 v_pk_fma_f32 per lane
      f32x2 acc0 = {0.f, 0.f}, acc1 = {0.f, 0.f};
      f32x2 acc2 = {0.f, 0.f}, acc3 = {0.f, 0.f};
#pragma unroll
      for (int cc = 0; cc < 16; ++cc) {
        asm("v_pk_fma_f32 %0, %1, %2, %0" : "+v"(acc0) : "v"(Wreg[0][cc]), "v"(hv[cc]));
        asm("v_pk_fma_f32 %0, %1, %2, %0" : "+v"(acc1) : "v"(Wreg[1][cc]), "v"(hv[cc]));
        asm("v_pk_fma_f32 %0, %1, %2, %0" : "+v"(acc2) : "v"(Wreg[2][cc]), "v"(hv[cc]));
        asm("v_pk_fma_f32 %0, %1, %2, %0" : "+v"(acc3) : "v"(Wreg[3][cc]), "v"(hv[cc]));
      }
      float* pbuf = &part[(s & 1) * PBUF];
      pbuf[pw0       ] = acc0.x + acc0.y;
      pbuf[pw0 +  640] = acc1.x + acc1.y;
      pbuf[pw0 + 1280] = acc2.x + acc2.y;
      pbuf[pw0 + 1920] = acc3.x + acc3.y;

      asm volatile("s_waitcnt lgkmcnt(0)" ::: "memory");
      __builtin_amdgcn_s_barrier();
      __builtin_amdgcn_sched_barrier(0);

      // ---- reduce: every lane sums all 8 slots of its output (no shfl)
      const f32x2* prow = (const f32x2*)&pbuf[PSTR * ocol];
      f32x2 p0 = prow[0], p1 = prow[1], p2 = prow[2], p3 = prow[3];
      f32x2 q01 = p0 + p1;          // v_pk_add_f32
      f32x2 q23 = p2 + p3;
      f32x2 qq = q01 + q23;
      float hn = tanh_fast((qq.x + qq.y) + xp_cur + bias);
      if (lane < 32) {
        hbuf[ocol] = hn;
        ybuf[ss * Hn + ocol] = hn;   // LDS only; banks 0..31, conflict-free
      }
      xp_cur = xp_n1;
      xp_n1 = xp_n2;

      // ---- wave-local hv reload (only this wave's own 32 outputs)
      __builtin_amdgcn_wave_barrier();   // keep reads after the masked write
#pragma unroll
      for (int j = 0; j < 8; ++j) {
        float4 v = *(const float4*)&hbuf[32 * w + 4 * j];
        hv[2 * j + 0] = f32x2{v.x, v.y};
        hv[2 * j + 1] = f32x2{v.z, v.w};
      }
    }

    // ---- flush y chunk: LDS -> global, coalesced 16B stores
    __syncthreads();                    // all waves' ybuf writes visible
#pragma unroll
    for (int i = 0; i < 4; ++i) {
      int idx = t + 512 * i;            // 0..2047 = 32 rows x 64 float4
      int row = idx >> 6;
      int c4 = (idx & 63) << 2;
      f32x4 v = *(const f32x4*)&ybuf[row * Hn + c4];
      float* gp = &y_b[(size_t)(s0 + row) * Hn + c4];
      if (Y_SC1) stg_dev4(gp, v);       // L3 write-through (proj2 consumes)
      else       *(f32x4*)gp = v;       // final output, normal cached
    }
    // wave-order guarantees flush reads precede next chunk's ybuf writes

    if (pub) publish(pub, (unsigned)(c + 1), t);
  }

  if (lane < 32) hfin_b[ocol] = hbuf[ocol];
}

// ---------------------------------------------------------------------------
// Projection worker, full width: one block per (layer, batch). Per chunk:
//   C[32,256] = A[32,256] * W[256,256]^T + bias as 4 64-wide tiles,
//   k ascending (summation order identical to all rounds -> absmax-stable).
// A,W normal cached; C (xp) coalesced 16B sc1 stores. ~8us/chunk << ~26us
// rec cadence (r8: 1-block proj never gates). proj1 paced by rec1's y1
// flag (lookahead PACE+1) to spread its power over the span.
// ---------------------------------------------------------------------------
__device__ void proj_body(const float* __restrict__ Ab,
                          const float* __restrict__ W,
                          const float* __restrict__ bias,
                          float* __restrict__ Cb,
                          unsigned* waitf, unsigned* pace, unsigned* pub,
                          float* smem) {
  const int t = threadIdx.x;
  const int tx = t & 15;    // 4 cols each
  const int ty = t >> 4;    // 0..31, 1 row each
  float (*As)[34] = (float(*)[34])smem;              // [64 k][32 m]
  float (*Bs)[68] = (float(*)[68])(smem + 64 * 34);  // [64 k][64 n]

  for (int c = 0; c < NCHUNK; ++c) {
    if (t == 0) {
      if (waitf) poll_ge(waitf, c + 1);
      if (pace && c > PACE) poll_ge(pace, (unsigned)(c - PACE));
    }
    __syncthreads();

    const float* A = Ab + (size_t)(c * CHUNK) * Hn;
    float* C = Cb + (size_t)(c * CHUNK) * Hn;

    for (int nt = 0; nt < 4; ++nt) {
      const int n0 = nt * 64;
      float acc[4] = {0.f, 0.f, 0.f, 0.f};
      for (int kc = 0; kc < Hn; kc += 64) {
        {
          int mm = t >> 4;               // 0..31
          int kk = (t & 15) << 2;
          float4 av = *(const float4*)&A[(size_t)mm * Hn + kc + kk];
          As[kk + 0][mm] = av.x; As[kk + 1][mm] = av.y;
          As[kk + 2][mm] = av.z; As[kk + 3][mm] = av.w;
        }
#pragma unroll
        for (int r = 0; r < 2; ++r) {
          int idx = t + 512 * r;         // 0..1023 -> 64 W-rows x 16 float4
          int mm = idx >> 4;
          int kk = (idx & 15) << 2;
          float4 wv = *(const float4*)&W[(size_t)(n0 + mm) * Hn + kc + kk];
          Bs[kk + 0][mm] = wv.x; Bs[kk + 1][mm] = wv.y;
          Bs[kk + 2][mm] = wv.z; Bs[kk + 3][mm] = wv.w;
        }
        __syncthreads();
#pragma unroll
        for (int k = 0; k < 64; ++k) {
          float a = As[k][ty];
          float4 bv = *(const float4*)&Bs[k][tx << 2];
          acc[0] += a * bv.x; acc[1] += a * bv.y;
          acc[2] += a * bv.z; acc[3] += a * bv.w;
        }
        __syncthreads();
      }
      float4 bb = *(const float4*)&bias[n0 + (tx << 2)];
      f32x4 ov;
      ov.x = acc[0] + bb.x; ov.y = acc[1] + bb.y;
      ov.z = acc[2] + bb.z; ov.w = acc[3] + bb.w;
      stg_dev4(&C[(size_t)ty * Hn + n0 + (tx << 2)], ov);
    }

    publish(pub, (unsigned)(c + 1), t);
  }
}

// ---------------------------------------------------------------------------
// Fused pipeline kernel. 128 blocks x 512 threads:
//   [  0, 32): rec1, batch b   polls xp1[b], publishes y1[b]
//   [ 32, 64): rec2, batch b   polls xp2[b]
//   [ 64, 96): proj1, batch b  paced by y1[b]; publishes xp1[b]
//   [ 96,128): proj2, batch b  polls y1[b]; publishes xp2[b]
// In-place xp reuse is flag-ordered: proj1[c] -> rec1[c] -> (y1 flag) ->
// proj2[c] -> rec2[c]; rec1's 2-row lookahead into c+1 is disjoint and
// sc1-reloaded post-flag. proj1 pacing cannot deadlock (chunks 0..PACE are
// unconditional; rec1 chunk c needs only xp1 <= c).
// ---------------------------------------------------------------------------
__global__ __launch_bounds__(512)
__attribute__((amdgpu_waves_per_eu(2, 2)))
void fused(
    const float* __restrict__ x, const float* __restrict__ h0,
    const float* __restrict__ Wih, const float* __restrict__ Whh,
    const float* __restrict__ bih, const float* __restrict__ bhh,
    float* __restrict__ yout, float* __restrict__ fin,
    float* __restrict__ xpws) {
  // rec: part (2*PBUF=5120) + hbuf (256) + ybuf (CHUNK*Hn=8192) = 13568 f
  // proj: As 64*34 + Bs 64*68 = 6528 f
  __shared__ float smem[2 * PBUF + Hn + CHUNK * Hn];   // 54.3 KB
  const int bid = blockIdx.x;

  if (bid < 32) {
    const int b = bid;
    rec_body<false, true>(xpws + (size_t)b * Sn * Hn, Whh, bhh,
                          h0 + (size_t)b * Hn,
                          yout + (size_t)b * Sn * Hn, fin + (size_t)b * Hn,
                          &g_flags[(0 * Bn + b) * FPAD],
                          &g_flags[(1 * Bn + b) * FPAD],
                          smem, smem + 2 * PBUF, smem + 2 * PBUF + Hn);
  } else if (bid < 64) {
    const int b = bid - 32;
    rec_body<true, false>(xpws + (size_t)b * Sn * Hn, Whh + Hn * Hn, bhh + Hn,
                          h0 + (size_t)Bn * Hn + (size_t)b * Hn,
                          yout + (size_t)b * Sn * Hn,
                          fin + (size_t)Bn * Hn + (size_t)b * Hn,
                          &g_flags[(2 * Bn + b) * FPAD], nullptr,
                          smem, smem + 2 * PBUF, smem + 2 * PBUF + Hn);
  } else if (bid < 96) {
    const int b = bid - 64;
    proj_body(x + (size_t)b * Sn * Hn, Wih, bih, xpws + (size_t)b * Sn * Hn,
              nullptr, &g_flags[(1 * Bn + b) * FPAD],
              &g_flags[(0 * Bn + b) * FPAD], smem);
  } else {
    const int b = bid - 96;
    proj_body(yout + (size_t)b * Sn * Hn, Wih + Hn * Hn, bih + Hn,
              xpws + (size_t)b * Sn * Hn,
              &g_flags[(1 * Bn + b) * FPAD], nullptr,
              &g_flags[(2 * Bn + b) * FPAD], smem);
  }
}

// ---------------------------------------------------------------------------
// Launch: zero flags, then the single fully-pipelined kernel.
// ws needs Bn*Sn*Hn*4 = 64 MiB (xp buffer, shared by both layers in-place).
// ---------------------------------------------------------------------------
extern "C" void kernel_launch(void* const* d_in, const int* in_sizes, int n_in,
                              void* d_out, int out_size, void* d_ws, size_t ws_size,
                              hipStream_t stream) {
  const float* x   = (const float*)d_in[0];
  const float* h0  = (const float*)d_in[1];
  const float* Wih = (const float*)d_in[2];
  const float* Whh = (const float*)d_in[3];
  const float* bih = (const float*)d_in[4];
  const float* bhh = (const float*)d_in[5];

  float* out = (float*)d_out;
  float* yout = out;                              // [Bn,Sn,Hn]
  float* fin  = out + (size_t)Bn * Sn * Hn;       // [Ln,Bn,Hn]
  float* xpws = (float*)d_ws;                     // [Bn,Sn,Hn] scratch

  zero_flags_k<<<1, 128, 0, stream>>>();
  fused<<<128, 512, 0, stream>>>(x, h0, Wih, Whh, bih, bhh, yout, fin, xpws);
}

// Round 14
// 1497.748 us; speedup vs baseline: 1.7666x; 1.7666x over previous
//
#include <hip/hip_runtime.h>
#include <cstddef>

#define Bn 32
#define Sn 2048
#define Hn 256
#define Ln 2
#define CHUNK 32
#define NCHUNK (Sn / CHUNK)   // 64
#define PACE 2                // proj1 runs at most PACE+1 chunks ahead of rec1

#define PSTR 10
#define PBUF (Hn * PSTR)      // 2560 words per partial buffer

#define FPAD 32               // one flag per 128B line
#define NFL (5 * Bn)          // 2 xp1-half + 1 y1 + 2 xp2-half per batch

typedef float f32x2 __attribute__((ext_vector_type(2)));
typedef float f32x4 __attribute__((ext_vector_type(4)));

// ---------------------------------------------------------------------------
// ZERO-FENCE pipeline, r12 grid + r13 coalesced agent-scope traffic.
//  - producers publish via 16B global_store_dwordx4 sc1 (write-through to
//    L3; 4x fewer transactions than r12's scalar stg_dev)
//  - rec y accumulates in LDS ybuf; per-chunk coalesced flush (removes the
//    per-step global store from the rec serial loop)
//  - consumers read normal-cached except provable stale-L2 cases (rec2's xp
//    aliases co-XCD rec1's cached xp1; both recs' 2 boundary prefetch rows)
//  - proj split 2-way per (layer,batch): r5/r13 proved 1 serial full-width
//    block GATES the pipe (P > cadence); halves are ~13us << 26.6us cadence
// Flag slots: (0..1,b) xp1 half j | (2,b) y1 done (also paces proj1) |
// (3..4,b) xp2 half j.
// ---------------------------------------------------------------------------
__device__ unsigned g_flags[NFL * FPAD];

__global__ void zero_flags_k() {
  int i = threadIdx.x;
  if (i < NFL)
    __hip_atomic_store(&g_flags[i * FPAD], 0u, __ATOMIC_RELAXED,
                       __HIP_MEMORY_SCOPE_AGENT);
}

__device__ __forceinline__ float tanh_fast(float x) {
  // tanh(x) = 1 - 2/(exp(2x)+1); saturates correctly at +/-inf
  float e = __expf(2.0f * x);
  return 1.0f - 2.0f / (e + 1.0f);
}

// sc1 (agent-scope) relaxed scalar load: bypasses non-coherent L2.
__device__ __forceinline__ float ldg_dev(const float* p) {
  return __hip_atomic_load(p, __ATOMIC_RELAXED, __HIP_MEMORY_SCOPE_AGENT);
}
// coalesced 16B agent-scope store (write-through to the L3 coherence point)
__device__ __forceinline__ void stg_dev4(float* p, f32x4 v) {
  asm volatile("global_store_dwordx4 %0, %1, off sc1"
               :: "v"(p), "v"(v) : "memory");
}

// pure poll over n flags (stride Bn*FPAD apart). NO fence. s_sleep(32):
// only truly-waiting blocks sleep; steady-state polls return immediately.
__device__ __forceinline__ void poll_ge_n(unsigned* base, int n, unsigned tgt) {
  for (int q = 0; q < n; ++q) {
    unsigned* f = base + (size_t)q * Bn * FPAD;
    while (__hip_atomic_load(f, __ATOMIC_RELAXED, __HIP_MEMORY_SCOPE_AGENT) < tgt)
      __builtin_amdgcn_s_sleep(32);
  }
}

// publisher: drain (sc1 write-through) stores, barrier, t0 stores flag.
__device__ __forceinline__ void publish(unsigned* f, unsigned val, int t) {
  asm volatile("s_waitcnt vmcnt(0)" ::: "memory");
  __syncthreads();
  if (t == 0)
    __hip_atomic_store(f, val, __ATOMIC_RELAXED, __HIP_MEMORY_SCOPE_AGENT);
}

// ---------------------------------------------------------------------------
// Recurrence body — r11/r12 step arithmetic unchanged (pk_fma FMA,
// stride-10 swizzled slot-major partials, no-shfl 8-slot reduce, hbuf
// h-exchange, single raw s_barrier/step, depth-2 xp prefetch). r13's ybuf:
// y goes to LDS in the loop (conflict-free), flushed per chunk as 16B
// coalesced stores (sc1 for rec1 -> proj2 consumes; cached for rec2 final).
// Flush ordering: the next chunk's poll+syncthreads orders the next ybuf
// writes after this flush's reads.
// ---------------------------------------------------------------------------
template <bool XP_SC1, bool Y_SC1>
__device__ void rec_body(const float* __restrict__ xp_b,
                         const float* __restrict__ Whh,
                         const float* __restrict__ bhh,
                         const float* __restrict__ h0_b,
                         float* __restrict__ y_b,
                         float* __restrict__ hfin_b,
                         unsigned* wbase, int nw, unsigned* pub,
                         float* part, float* hbuf, float* ybuf) {
  const int t = threadIdx.x;
  const int lane = t & 63;
  const int w = t >> 6;                   // 0..7
  const int ocol = 32 * w + (lane & 31);  // output this lane reduces

  // Wreg[r][c2] = (Whh[lane+64r][32w+2c2], Whh[lane+64r][32w+2c2+1])
  f32x2 Wreg[4][16];
#pragma unroll
  for (int r = 0; r < 4; ++r)
#pragma unroll
    for (int q = 0; q < 8; ++q) {
      float4 v = *(const float4*)&Whh[(size_t)(lane + 64 * r) * Hn + 32 * w + 4 * q];
      Wreg[r][2 * q + 0] = f32x2{v.x, v.y};
      Wreg[r][2 * q + 1] = f32x2{v.z, v.w};
    }
#pragma unroll
  for (int r = 0; r < 4; ++r)
#pragma unroll
    for (int c = 0; c < 16; ++c)
      asm("" : "+v"(Wreg[r][c]));

  // partial write base: row = lane(+64r), slot = w ^ ((lane>>3)&3)
  const int pw0 = PSTR * lane + (w ^ ((lane >> 3) & 3));
  const float bias = bhh[ocol];

  f32x2 hv[16];
#pragma unroll
  for (int j = 0; j < 8; ++j) {
    float4 v = *(const float4*)&h0_b[32 * w + 4 * j];
    hv[2 * j + 0] = f32x2{v.x, v.y};
    hv[2 * j + 1] = f32x2{v.z, v.w};
  }

  for (int c = 0; c < NCHUNK; ++c) {
    // acquire this chunk's xp halves: pure poll, no fence
    if (t == 0) poll_ge_n(wbase, nw, c + 1);
    __syncthreads();

    const int s0 = c * CHUNK;
    // sc1 reload of the two rows our pre-flag cross-chunk prefetch touched
    float xp_cur = ldg_dev(&xp_b[(size_t)s0 * Hn + ocol]);
    float xp_n1  = ldg_dev(&xp_b[(size_t)(s0 + 1) * Hn + ocol]);

    for (int ss = 0; ss < CHUNK; ++ss) {
      const int s = s0 + ss;
      // depth-2 prefetch: consumed two steps later
      float xp_n2 = 0.0f;
      if (s + 2 < Sn)
        xp_n2 = XP_SC1 ? ldg_dev(&xp_b[(size_t)(s + 2) * Hn + ocol])
                       : xp_b[(size_t)(s + 2) * Hn + ocol];

      // ---- FMA phase: 64 v_pk_fma_f32 per lane
      f32x2 acc0 = {0.f, 0.f}, acc1 = {0.f, 0.f};
      f32x2 acc2 = {0.f, 0.f}, acc3 = {0.f, 0.f};
#pragma unroll
      for (int cc = 0; cc < 16; ++cc) {
        asm("v_pk_fma_f32 %0, %1, %2, %0" : "+v"(acc0) : "v"(Wreg[0][cc]), "v"(hv[cc]));
        asm("v_pk_fma_f32 %0, %1, %2, %0" : "+v"(acc1) : "v"(Wreg[1][cc]), "v"(hv[cc]));
        asm("v_pk_fma_f32 %0, %1, %2, %0" : "+v"(acc2) : "v"(Wreg[2][cc]), "v"(hv[cc]));
        asm("v_pk_fma_f32 %0, %1, %2, %0" : "+v"(acc3) : "v"(Wreg[3][cc]), "v"(hv[cc]));
      }
      float* pbuf = &part[(s & 1) * PBUF];
      pbuf[pw0       ] = acc0.x + acc0.y;
      pbuf[pw0 +  640] = acc1.x + acc1.y;
      pbuf[pw0 + 1280] = acc2.x + acc2.y;
      pbuf[pw0 + 1920] = acc3.x + acc3.y;

      asm volatile("s_waitcnt lgkmcnt(0)" ::: "memory");
      __builtin_amdgcn_s_barrier();
      __builtin_amdgcn_sched_barrier(0);

      // ---- reduce: every lane sums all 8 slots of its output (no shfl)
      const f32x2* prow = (const f32x2*)&pbuf[PSTR * ocol];
      f32x2 p0 = prow[0], p1 = prow[1], p2 = prow[2], p3 = prow[3];
      f32x2 q01 = p0 + p1;          // v_pk_add_f32
      f32x2 q23 = p2 + p3;
      f32x2 qq = q01 + q23;
      float hn = tanh_fast((qq.x + qq.y) + xp_cur + bias);
      if (lane < 32) {
        hbuf[ocol] = hn;
        ybuf[ss * Hn + ocol] = hn;   // LDS only; conflict-free
      }
      xp_cur = xp_n1;
      xp_n1 = xp_n2;

      // ---- wave-local hv reload (only this wave's own 32 outputs)
      __builtin_amdgcn_wave_barrier();   // keep reads after the masked write
#pragma unroll
      for (int j = 0; j < 8; ++j) {
        float4 v = *(const float4*)&hbuf[32 * w + 4 * j];
        hv[2 * j + 0] = f32x2{v.x, v.y};
        hv[2 * j + 1] = f32x2{v.z, v.w};
      }
    }

    // ---- flush y chunk: LDS -> global, coalesced 16B stores
    __syncthreads();                    // all waves' ybuf writes visible
#pragma unroll
    for (int i = 0; i < 4; ++i) {
      int idx = t + 512 * i;            // 0..2047 = 32 rows x 64 float4
      int row = idx >> 6;
      int c4 = (idx & 63) << 2;
      f32x4 v = *(const f32x4*)&ybuf[row * Hn + c4];
      float* gp = &y_b[(size_t)(s0 + row) * Hn + c4];
      if (Y_SC1) stg_dev4(gp, v);       // L3 write-through (proj2 consumes)
      else       *(f32x4*)gp = v;       // final output, normal cached
    }

    if (pub) publish(pub, (unsigned)(c + 1), t);
  }

  if (lane < 32) hfin_b[ocol] = hbuf[ocol];
}

// ---------------------------------------------------------------------------
// Projection worker (r12 split restored): one block per (layer,batch,
// N-half), 2 tiles each. Per chunk: C[32, 2x64] = A[32,256]*W^T + bias,
// k ascending (absmax-stable). A,W normal cached; C via one 16B sc1 store.
// ~13us/chunk << 26.6us rec cadence -> never gates (r8; r13 proved the
// 1-block variant DOES gate). proj1 paced by rec1's y1 flag.
// ---------------------------------------------------------------------------
__device__ void proj_body(const float* __restrict__ Ab,
                          const float* __restrict__ W,
                          const float* __restrict__ bias,
                          float* __restrict__ Cb,
                          unsigned* waitf, unsigned* pace, unsigned* pub,
                          int nt0, int nt1,
                          float* smem) {
  const int t = threadIdx.x;
  const int tx = t & 15;    // 4 cols each
  const int ty = t >> 4;    // 0..31, 1 row each
  float (*As)[34] = (float(*)[34])smem;              // [64 k][32 m]
  float (*Bs)[68] = (float(*)[68])(smem + 64 * 34);  // [64 k][64 n]

  for (int c = 0; c < NCHUNK; ++c) {
    if (t == 0) {
      if (waitf) poll_ge_n(waitf, 1, c + 1);
      if (pace && c > PACE) poll_ge_n(pace, 1, (unsigned)(c - PACE));
    }
    __syncthreads();

    const float* A = Ab + (size_t)(c * CHUNK) * Hn;
    float* C = Cb + (size_t)(c * CHUNK) * Hn;

    for (int nt = nt0; nt < nt1; ++nt) {
      const int n0 = nt * 64;
      float acc[4] = {0.f, 0.f, 0.f, 0.f};
      for (int kc = 0; kc < Hn; kc += 64) {
        {
          int mm = t >> 4;               // 0..31
          int kk = (t & 15) << 2;
          float4 av = *(const float4*)&A[(size_t)mm * Hn + kc + kk];
          As[kk + 0][mm] = av.x; As[kk + 1][mm] = av.y;
          As[kk + 2][mm] = av.z; As[kk + 3][mm] = av.w;
        }
#pragma unroll
        for (int r = 0; r < 2; ++r) {
          int idx = t + 512 * r;         // 0..1023 -> 64 W-rows x 16 float4
          int mm = idx >> 4;
          int kk = (idx & 15) << 2;
          float4 wv = *(const float4*)&W[(size_t)(n0 + mm) * Hn + kc + kk];
          Bs[kk + 0][mm] = wv.x; Bs[kk + 1][mm] = wv.y;
          Bs[kk + 2][mm] = wv.z; Bs[kk + 3][mm] = wv.w;
        }
        __syncthreads();
#pragma unroll
        for (int k = 0; k < 64; ++k) {
          float a = As[k][ty];
          float4 bv = *(const float4*)&Bs[k][tx << 2];
          acc[0] += a * bv.x; acc[1] += a * bv.y;
          acc[2] += a * bv.z; acc[3] += a * bv.w;
        }
        __syncthreads();
      }
      float4 bb = *(const float4*)&bias[n0 + (tx << 2)];
      f32x4 ov;
      ov.x = acc[0] + bb.x; ov.y = acc[1] + bb.y;
      ov.z = acc[2] + bb.z; ov.w = acc[3] + bb.w;
      stg_dev4(&C[(size_t)ty * Hn + n0 + (tx << 2)], ov);
    }

    publish(pub, (unsigned)(c + 1), t);
  }
}

// ---------------------------------------------------------------------------
// Fused pipeline kernel. 192 blocks x 512 threads (r12 grid):
//   [  0, 32): rec1, batch b      polls xp1[b] (2 flags), publishes y1[b]
//   [ 32, 64): rec2, batch b      polls xp2[b] (2 flags)
//   [ 64,128): proj1 (b, half j)  paced by y1[b]; publishes xp1[b] half j
//   [128,192): proj2 (b, half j)  polls y1[b]; publishes xp2[b] half j
// In-place xp reuse flag-ordered: proj1[c] -> rec1[c] -> (y1) -> proj2[c]
// -> rec2[c]; rec1's 2-row lookahead into c+1 is disjoint + sc1-reloaded.
// proj1 pacing cannot deadlock (chunks 0..PACE unconditional).
// ---------------------------------------------------------------------------
__global__ __launch_bounds__(512)
__attribute__((amdgpu_waves_per_eu(2, 2)))
void fused(
    const float* __restrict__ x, const float* __restrict__ h0,
    const float* __restrict__ Wih, const float* __restrict__ Whh,
    const float* __restrict__ bih, const float* __restrict__ bhh,
    float* __restrict__ yout, float* __restrict__ fin,
    float* __restrict__ xpws) {
  // rec: part (5120) + hbuf (256) + ybuf (8192) = 13568 f = 54.3 KB
  // proj: As 64*34 + Bs 64*68 = 6528 f
  __shared__ float smem[2 * PBUF + Hn + CHUNK * Hn];
  const int bid = blockIdx.x;

  if (bid < 32) {
    const int b = bid;
    rec_body<false, true>(xpws + (size_t)b * Sn * Hn, Whh, bhh,
                          h0 + (size_t)b * Hn,
                          yout + (size_t)b * Sn * Hn, fin + (size_t)b * Hn,
                          &g_flags[(0 * Bn + b) * FPAD], 2,
                          &g_flags[(2 * Bn + b) * FPAD],
                          smem, smem + 2 * PBUF, smem + 2 * PBUF + Hn);
  } else if (bid < 64) {
    const int b = bid - 32;
    rec_body<true, false>(xpws + (size_t)b * Sn * Hn, Whh + Hn * Hn, bhh + Hn,
                          h0 + (size_t)Bn * Hn + (size_t)b * Hn,
                          yout + (size_t)b * Sn * Hn,
                          fin + (size_t)Bn * Hn + (size_t)b * Hn,
                          &g_flags[(3 * Bn + b) * FPAD], 2, nullptr,
                          smem, smem + 2 * PBUF, smem + 2 * PBUF + Hn);
  } else if (bid < 128) {
    const int q = bid - 64;
    const int b = q & 31, j = q >> 5;    // half j: tiles 2j..2j+1
    proj_body(x + (size_t)b * Sn * Hn, Wih, bih, xpws + (size_t)b * Sn * Hn,
              nullptr, &g_flags[(2 * Bn + b) * FPAD],
              &g_flags[((0 + j) * Bn + b) * FPAD],
              2 * j, 2 * j + 2, smem);
  } else {
    const int q = bid - 128;
    const int b = q & 31, j = q >> 5;    // half j: tiles 2j..2j+1
    proj_body(yout + (size_t)b * Sn * Hn, Wih + Hn * Hn, bih + Hn,
              xpws + (size_t)b * Sn * Hn,
              &g_flags[(2 * Bn + b) * FPAD], nullptr,
              &g_flags[((3 + j) * Bn + b) * FPAD],
              2 * j, 2 * j + 2, smem);
  }
}

// ---------------------------------------------------------------------------
// Launch: zero flags, then the single fully-pipelined kernel.
// ws needs Bn*Sn*Hn*4 = 64 MiB (xp buffer, shared by both layers in-place).
// ---------------------------------------------------------------------------
extern "C" void kernel_launch(void* const* d_in, const int* in_sizes, int n_in,
                              void* d_out, int out_size, void* d_ws, size_t ws_size,
                              hipStream_t stream) {
  const float* x   = (const float*)d_in[0];
  const float* h0  = (const float*)d_in[1];
  const float* Wih = (const float*)d_in[2];
  const float* Whh = (const float*)d_in[3];
  const float* bih = (const float*)d_in[4];
  const float* bhh = (const float*)d_in[5];

  float* out = (float*)d_out;
  float* yout = out;                              // [Bn,Sn,Hn]
  float* fin  = out + (size_t)Bn * Sn * Hn;       // [Ln,Bn,Hn]
  float* xpws = (float*)d_ws;                     // [Bn,Sn,Hn] scratch

  zero_flags_k<<<1, 256, 0, stream>>>();
  fused<<<192, 512, 0, stream>>>(x, h0, Wih, Whh, bih, bhh, yout, fin, xpws);
}

// Round 15
// 1445.496 us; speedup vs baseline: 1.8305x; 1.0361x over previous
//
#include <hip/hip_runtime.h>
#include <cstddef>

#define Bn 32
#define Sn 2048
#define Hn 256
#define Ln 2
#define CHUNK 64
#define NCHUNK (Sn / CHUNK)   // 32
#define PACE 2                // proj1 runs at most PACE+1 chunks ahead of rec1

#define PSTR 10
#define PBUF (Hn * PSTR)      // 2560 words per partial buffer

#define FPAD 32               // one flag per 128B line
#define NFL (5 * Bn)          // 2 xp1-half + 1 y1 + 2 xp2-half per batch

typedef float f32x2 __attribute__((ext_vector_type(2)));
typedef float f32x4 __attribute__((ext_vector_type(4)));

// ---------------------------------------------------------------------------
// ZERO-FENCE pipeline (r14-proven: 1498us) with CHUNK=64 (r15: halve the
// per-chunk overheads -- poll + boundary sc1 loads + flush drain + publish
// cost ~2.5-3us each; 64 chunks -> 32).
//  - producers publish via 16B global_store_dwordx4 sc1 (write-through L3)
//  - rec y accumulates in LDS ybuf; per-chunk coalesced flush
//  - consumers read normal-cached except provable stale-L2 cases (rec2's xp
//    aliases co-XCD rec1's cached xp1; both recs' 2 boundary prefetch rows)
//  - proj split 2-way per (layer,batch): 1 serial full-width block GATES
//    (r5/r13); halves are ~26us/chunk < ~45us rec cadence at CHUNK=64
// Flag slots: (0..1,b) xp1 half j | (2,b) y1 done (also paces proj1) |
// (3..4,b) xp2 half j.
// ---------------------------------------------------------------------------
__device__ unsigned g_flags[NFL * FPAD];

__global__ void zero_flags_k() {
  int i = threadIdx.x;
  if (i < NFL)
    __hip_atomic_store(&g_flags[i * FPAD], 0u, __ATOMIC_RELAXED,
                       __HIP_MEMORY_SCOPE_AGENT);
}

__device__ __forceinline__ float tanh_fast(float x) {
  // tanh(x) = 1 - 2/(exp(2x)+1); saturates correctly at +/-inf
  float e = __expf(2.0f * x);
  return 1.0f - 2.0f / (e + 1.0f);
}

// sc1 (agent-scope) relaxed scalar load: bypasses non-coherent L2.
__device__ __forceinline__ float ldg_dev(const float* p) {
  return __hip_atomic_load(p, __ATOMIC_RELAXED, __HIP_MEMORY_SCOPE_AGENT);
}
// coalesced 16B agent-scope store (write-through to the L3 coherence point)
__device__ __forceinline__ void stg_dev4(float* p, f32x4 v) {
  asm volatile("global_store_dwordx4 %0, %1, off sc1"
               :: "v"(p), "v"(v) : "memory");
}

// pure poll over n flags (stride Bn*FPAD apart). NO fence. s_sleep(32):
// only truly-waiting blocks sleep; steady-state polls return immediately.
__device__ __forceinline__ void poll_ge_n(unsigned* base, int n, unsigned tgt) {
  for (int q = 0; q < n; ++q) {
    unsigned* f = base + (size_t)q * Bn * FPAD;
    while (__hip_atomic_load(f, __ATOMIC_RELAXED, __HIP_MEMORY_SCOPE_AGENT) < tgt)
      __builtin_amdgcn_s_sleep(32);
  }
}

// publisher: drain (sc1 write-through) stores, barrier, t0 stores flag.
__device__ __forceinline__ void publish(unsigned* f, unsigned val, int t) {
  asm volatile("s_waitcnt vmcnt(0)" ::: "memory");
  __syncthreads();
  if (t == 0)
    __hip_atomic_store(f, val, __ATOMIC_RELAXED, __HIP_MEMORY_SCOPE_AGENT);
}

// ---------------------------------------------------------------------------
// Recurrence body — r11/r14 step arithmetic unchanged (pk_fma FMA,
// stride-10 swizzled slot-major partials, no-shfl 8-slot reduce, hbuf
// h-exchange, single raw s_barrier/step, depth-2 xp prefetch). y goes to
// LDS ybuf in the loop (conflict-free), flushed per chunk as 16B coalesced
// stores (sc1 for rec1 -> proj2 consumes; cached for rec2 final).
// ---------------------------------------------------------------------------
template <bool XP_SC1, bool Y_SC1>
__device__ void rec_body(const float* __restrict__ xp_b,
                         const float* __restrict__ Whh,
                         const float* __restrict__ bhh,
                         const float* __restrict__ h0_b,
                         float* __restrict__ y_b,
                         float* __restrict__ hfin_b,
                         unsigned* wbase, int nw, unsigned* pub,
                         float* part, float* hbuf, float* ybuf) {
  const int t = threadIdx.x;
  const int lane = t & 63;
  const int w = t >> 6;                   // 0..7
  const int ocol = 32 * w + (lane & 31);  // output this lane reduces

  // Wreg[r][c2] = (Whh[lane+64r][32w+2c2], Whh[lane+64r][32w+2c2+1])
  f32x2 Wreg[4][16];
#pragma unroll
  for (int r = 0; r < 4; ++r)
#pragma unroll
    for (int q = 0; q < 8; ++q) {
      float4 v = *(const float4*)&Whh[(size_t)(lane + 64 * r) * Hn + 32 * w + 4 * q];
      Wreg[r][2 * q + 0] = f32x2{v.x, v.y};
      Wreg[r][2 * q + 1] = f32x2{v.z, v.w};
    }
#pragma unroll
  for (int r = 0; r < 4; ++r)
#pragma unroll
    for (int c = 0; c < 16; ++c)
      asm("" : "+v"(Wreg[r][c]));

  // partial write base: row = lane(+64r), slot = w ^ ((lane>>3)&3)
  const int pw0 = PSTR * lane + (w ^ ((lane >> 3) & 3));
  const float bias = bhh[ocol];

  f32x2 hv[16];
#pragma unroll
  for (int j = 0; j < 8; ++j) {
    float4 v = *(const float4*)&h0_b[32 * w + 4 * j];
    hv[2 * j + 0] = f32x2{v.x, v.y};
    hv[2 * j + 1] = f32x2{v.z, v.w};
  }

  for (int c = 0; c < NCHUNK; ++c) {
    // acquire this chunk's xp halves: pure poll, no fence
    if (t == 0) poll_ge_n(wbase, nw, c + 1);
    __syncthreads();

    const int s0 = c * CHUNK;
    // sc1 reload of the two rows our pre-flag cross-chunk prefetch touched
    float xp_cur = ldg_dev(&xp_b[(size_t)s0 * Hn + ocol]);
    float xp_n1  = ldg_dev(&xp_b[(size_t)(s0 + 1) * Hn + ocol]);

    for (int ss = 0; ss < CHUNK; ++ss) {
      const int s = s0 + ss;
      // depth-2 prefetch: consumed two steps later
      float xp_n2 = 0.0f;
      if (s + 2 < Sn)
        xp_n2 = XP_SC1 ? ldg_dev(&xp_b[(size_t)(s + 2) * Hn + ocol])
                       : xp_b[(size_t)(s + 2) * Hn + ocol];

      // ---- FMA phase: 64 v_pk_fma_f32 per lane
      f32x2 acc0 = {0.f, 0.f}, acc1 = {0.f, 0.f};
      f32x2 acc2 = {0.f, 0.f}, acc3 = {0.f, 0.f};
#pragma unroll
      for (int cc = 0; cc < 16; ++cc) {
        asm("v_pk_fma_f32 %0, %1, %2, %0" : "+v"(acc0) : "v"(Wreg[0][cc]), "v"(hv[cc]));
        asm("v_pk_fma_f32 %0, %1, %2, %0" : "+v"(acc1) : "v"(Wreg[1][cc]), "v"(hv[cc]));
        asm("v_pk_fma_f32 %0, %1, %2, %0" : "+v"(acc2) : "v"(Wreg[2][cc]), "v"(hv[cc]));
        asm("v_pk_fma_f32 %0, %1, %2, %0" : "+v"(acc3) : "v"(Wreg[3][cc]), "v"(hv[cc]));
      }
      float* pbuf = &part[(s & 1) * PBUF];
      pbuf[pw0       ] = acc0.x + acc0.y;
      pbuf[pw0 +  640] = acc1.x + acc1.y;
      pbuf[pw0 + 1280] = acc2.x + acc2.y;
      pbuf[pw0 + 1920] = acc3.x + acc3.y;

      asm volatile("s_waitcnt lgkmcnt(0)" ::: "memory");
      __builtin_amdgcn_s_barrier();
      __builtin_amdgcn_sched_barrier(0);

      // ---- reduce: every lane sums all 8 slots of its output (no shfl)
      const f32x2* prow = (const f32x2*)&pbuf[PSTR * ocol];
      f32x2 p0 = prow[0], p1 = prow[1], p2 = prow[2], p3 = prow[3];
      f32x2 q01 = p0 + p1;          // v_pk_add_f32
      f32x2 q23 = p2 + p3;
      f32x2 qq = q01 + q23;
      float hn = tanh_fast((qq.x + qq.y) + xp_cur + bias);
      if (lane < 32) {
        hbuf[ocol] = hn;
        ybuf[ss * Hn + ocol] = hn;   // LDS only; conflict-free
      }
      xp_cur = xp_n1;
      xp_n1 = xp_n2;

      // ---- wave-local hv reload (only this wave's own 32 outputs)
      __builtin_amdgcn_wave_barrier();   // keep reads after the masked write
#pragma unroll
      for (int j = 0; j < 8; ++j) {
        float4 v = *(const float4*)&hbuf[32 * w + 4 * j];
        hv[2 * j + 0] = f32x2{v.x, v.y};
        hv[2 * j + 1] = f32x2{v.z, v.w};
      }
    }

    // ---- flush y chunk: LDS -> global, coalesced 16B stores
    __syncthreads();                    // all waves' ybuf writes visible
#pragma unroll
    for (int i = 0; i < 8; ++i) {
      int idx = t + 512 * i;            // 0..4095 = 64 rows x 64 float4
      int row = idx >> 6;
      int c4 = (idx & 63) << 2;
      f32x4 v = *(const f32x4*)&ybuf[row * Hn + c4];
      float* gp = &y_b[(size_t)(s0 + row) * Hn + c4];
      if (Y_SC1) stg_dev4(gp, v);       // L3 write-through (proj2 consumes)
      else       *(f32x4*)gp = v;       // final output, normal cached
    }

    if (pub) publish(pub, (unsigned)(c + 1), t);
  }

  if (lane < 32) hfin_b[ocol] = hbuf[ocol];
}

// ---------------------------------------------------------------------------
// Projection worker: one block per (layer, batch, N-half), 2 tiles each.
// Per chunk: C[64, 2x64] = A[64,256]*W^T + bias, k ascending
// (absmax-stable). A,W normal cached; C via one 16B sc1 store per tile-row.
// ~26us/chunk < ~45us rec cadence -> never gates. proj1 paced by y1 flag.
// ---------------------------------------------------------------------------
__device__ void proj_body(const float* __restrict__ Ab,
                          const float* __restrict__ W,
                          const float* __restrict__ bias,
                          float* __restrict__ Cb,
                          unsigned* waitf, unsigned* pace, unsigned* pub,
                          int nt0, int nt1,
                          float* smem) {
  const int t = threadIdx.x;
  const int tx = t & 15;    // 4 cols each
  const int ty = t >> 4;    // 0..31, 2 rows each
  float (*As)[68] = (float(*)[68])smem;              // [64 k][64 m]
  float (*Bs)[68] = (float(*)[68])(smem + 64 * 68);  // [64 k][64 n]

  for (int c = 0; c < NCHUNK; ++c) {
    if (t == 0) {
      if (waitf) poll_ge_n(waitf, 1, c + 1);
      if (pace && c > PACE) poll_ge_n(pace, 1, (unsigned)(c - PACE));
    }
    __syncthreads();

    const float* A = Ab + (size_t)(c * CHUNK) * Hn;
    float* C = Cb + (size_t)(c * CHUNK) * Hn;

    for (int nt = nt0; nt < nt1; ++nt) {
      const int n0 = nt * 64;
      float acc[2][4] = {{0.f, 0.f, 0.f, 0.f}, {0.f, 0.f, 0.f, 0.f}};
      for (int kc = 0; kc < Hn; kc += 64) {
#pragma unroll
        for (int r = 0; r < 2; ++r) {
          int idx = t + 512 * r;         // 0..1023 -> 64 rows x 16 float4
          int mm = idx >> 4;
          int kk = (idx & 15) << 2;
          float4 av = *(const float4*)&A[(size_t)mm * Hn + kc + kk];
          As[kk + 0][mm] = av.x; As[kk + 1][mm] = av.y;
          As[kk + 2][mm] = av.z; As[kk + 3][mm] = av.w;
          float4 wv = *(const float4*)&W[(size_t)(n0 + mm) * Hn + kc + kk];
          Bs[kk + 0][mm] = wv.x; Bs[kk + 1][mm] = wv.y;
          Bs[kk + 2][mm] = wv.z; Bs[kk + 3][mm] = wv.w;
        }
        __syncthreads();
#pragma unroll
        for (int k = 0; k < 64; ++k) {
          float a0 = As[k][2 * ty], a1 = As[k][2 * ty + 1];
          float4 bv = *(const float4*)&Bs[k][tx << 2];
          acc[0][0] += a0 * bv.x; acc[0][1] += a0 * bv.y;
          acc[0][2] += a0 * bv.z; acc[0][3] += a0 * bv.w;
          acc[1][0] += a1 * bv.x; acc[1][1] += a1 * bv.y;
          acc[1][2] += a1 * bv.z; acc[1][3] += a1 * bv.w;
        }
        __syncthreads();
      }
      float4 bb = *(const float4*)&bias[n0 + (tx << 2)];
#pragma unroll
      for (int i = 0; i < 2; ++i) {
        f32x4 ov;
        ov.x = acc[i][0] + bb.x; ov.y = acc[i][1] + bb.y;
        ov.z = acc[i][2] + bb.z; ov.w = acc[i][3] + bb.w;
        stg_dev4(&C[(size_t)(2 * ty + i) * Hn + n0 + (tx << 2)], ov);
      }
    }

    publish(pub, (unsigned)(c + 1), t);
  }
}

// ---------------------------------------------------------------------------
// Fused pipeline kernel. 192 blocks x 512 threads (r12/r14 grid):
//   [  0, 32): rec1, batch b      polls xp1[b] (2 flags), publishes y1[b]
//   [ 32, 64): rec2, batch b      polls xp2[b] (2 flags)
//   [ 64,128): proj1 (b, half j)  paced by y1[b]; publishes xp1[b] half j
//   [128,192): proj2 (b, half j)  polls y1[b]; publishes xp2[b] half j
// In-place xp reuse flag-ordered: proj1[c] -> rec1[c] -> (y1) -> proj2[c]
// -> rec2[c]; rec1's 2-row lookahead into c+1 is disjoint + sc1-reloaded.
// proj1 pacing cannot deadlock (chunks 0..PACE unconditional).
// ---------------------------------------------------------------------------
__global__ __launch_bounds__(512)
__attribute__((amdgpu_waves_per_eu(2, 2)))
void fused(
    const float* __restrict__ x, const float* __restrict__ h0,
    const float* __restrict__ Wih, const float* __restrict__ Whh,
    const float* __restrict__ bih, const float* __restrict__ bhh,
    float* __restrict__ yout, float* __restrict__ fin,
    float* __restrict__ xpws) {
  // rec: part (5120) + hbuf (256) + ybuf (64*256=16384) = 21760 f = 87 KB
  // proj: As 64*68 + Bs 64*68 = 8704 f
  __shared__ float smem[2 * PBUF + Hn + CHUNK * Hn];
  const int bid = blockIdx.x;

  if (bid < 32) {
    const int b = bid;
    rec_body<false, true>(xpws + (size_t)b * Sn * Hn, Whh, bhh,
                          h0 + (size_t)b * Hn,
                          yout + (size_t)b * Sn * Hn, fin + (size_t)b * Hn,
                          &g_flags[(0 * Bn + b) * FPAD], 2,
                          &g_flags[(2 * Bn + b) * FPAD],
                          smem, smem + 2 * PBUF, smem + 2 * PBUF + Hn);
  } else if (bid < 64) {
    const int b = bid - 32;
    rec_body<true, false>(xpws + (size_t)b * Sn * Hn, Whh + Hn * Hn, bhh + Hn,
                          h0 + (size_t)Bn * Hn + (size_t)b * Hn,
                          yout + (size_t)b * Sn * Hn,
                          fin + (size_t)Bn * Hn + (size_t)b * Hn,
                          &g_flags[(3 * Bn + b) * FPAD], 2, nullptr,
                          smem, smem + 2 * PBUF, smem + 2 * PBUF + Hn);
  } else if (bid < 128) {
    const int q = bid - 64;
    const int b = q & 31, j = q >> 5;    // half j: tiles 2j..2j+1
    proj_body(x + (size_t)b * Sn * Hn, Wih, bih, xpws + (size_t)b * Sn * Hn,
              nullptr, &g_flags[(2 * Bn + b) * FPAD],
              &g_flags[((0 + j) * Bn + b) * FPAD],
              2 * j, 2 * j + 2, smem);
  } else {
    const int q = bid - 128;
    const int b = q & 31, j = q >> 5;    // half j: tiles 2j..2j+1
    proj_body(yout + (size_t)b * Sn * Hn, Wih + Hn * Hn, bih + Hn,
              xpws + (size_t)b * Sn * Hn,
              &g_flags[(2 * Bn + b) * FPAD], nullptr,
              &g_flags[((3 + j) * Bn + b) * FPAD],
              2 * j, 2 * j + 2, smem);
  }
}

// ---------------------------------------------------------------------------
// Launch: zero flags, then the single fully-pipelined kernel.
// ws needs Bn*Sn*Hn*4 = 64 MiB (xp buffer, shared by both layers in-place).
// ---------------------------------------------------------------------------
extern "C" void kernel_launch(void* const* d_in, const int* in_sizes, int n_in,
                              void* d_out, int out_size, void* d_ws, size_t ws_size,
                              hipStream_t stream) {
  const float* x   = (const float*)d_in[0];
  const float* h0  = (const float*)d_in[1];
  const float* Wih = (const float*)d_in[2];
  const float* Whh = (const float*)d_in[3];
  const float* bih = (const float*)d_in[4];
  const float* bhh = (const float*)d_in[5];

  float* out = (float*)d_out;
  float* yout = out;                              // [Bn,Sn,Hn]
  float* fin  = out + (size_t)Bn * Sn * Hn;       // [Ln,Bn,Hn]
  float* xpws = (float*)d_ws;                     // [Bn,Sn,Hn] scratch

  zero_flags_k<<<1, 256, 0, stream>>>();
  fused<<<192, 512, 0, stream>>>(x, h0, Wih, Whh, bih, bhh, yout, fin, xpws);
}